// Round 1
// baseline (297.617 us; speedup 1.0000x reference)
//
#include <hip/hip_runtime.h>

typedef __attribute__((ext_vector_type(8))) short bf16x8;
typedef __attribute__((ext_vector_type(4))) float f32x4;

// fp32 -> bf16 (round-to-nearest-even), finite inputs only
__device__ __forceinline__ unsigned short f2b(float f) {
  union { float f; unsigned u; } v; v.f = f;
  return (unsigned short)((v.u + 0x7FFFu + ((v.u >> 16) & 1u)) >> 16);
}

__global__ void cvt4(const float* __restrict__ in, unsigned short* __restrict__ out, int n4) {
  int i = blockIdx.x * 256 + threadIdx.x;
  if (i >= n4) return;
  float4 f = reinterpret_cast<const float4*>(in)[i];
  ushort4 o;
  o.x = f2b(f.x); o.y = f2b(f.y); o.z = f2b(f.z); o.w = f2b(f.w);
  reinterpret_cast<ushort4*>(out)[i] = o;
}

// C = A * B^T.  A: [M][K] bf16 row-major, Bm: [N][K] bf16 row-major.
// mode 0: qkv scatter epilogue -> Qb/Kb [B,H,T,D], Vt [B,H,D,T] (bf16)
// mode 1: fp32 row-major [M][N] to outf
#define BM 128
#define BN 128
#define BK 64
#define LDP 88  // padded LDS row pitch (elements): 176B = 16B-aligned, breaks bank conflicts

__global__ __launch_bounds__(256, 2)
void gemm_nt(const unsigned short* __restrict__ A,
             const unsigned short* __restrict__ Bm,
             int M, int N, int K, int mode,
             unsigned short* __restrict__ qb,
             unsigned short* __restrict__ kb_,
             unsigned short* __restrict__ vt,
             float* __restrict__ outf) {
  __shared__ unsigned short As[BM * LDP];
  __shared__ unsigned short Bs[BN * LDP];
  int tid = threadIdx.x;
  int wave = tid >> 6, lane = tid & 63;
  int quad = lane >> 4, l16 = lane & 15;
  int m0 = blockIdx.x * BM, n0 = blockIdx.y * BN;
  int wm = (wave & 1) * 64, wn = (wave >> 1) * 64;

  f32x4 acc[4][4] = {};

  int lr = tid >> 3;        // 0..31 (row within 32-row group)
  int lc = (tid & 7) * 8;   // 0,8,...,56 (k-offset)

  for (int k0 = 0; k0 < K; k0 += BK) {
    __syncthreads();
#pragma unroll
    for (int rr = 0; rr < 4; ++rr) {
      int row = lr + rr * 32;
      bf16x8 av = *reinterpret_cast<const bf16x8*>(A + (size_t)(m0 + row) * K + k0 + lc);
      *reinterpret_cast<bf16x8*>(As + row * LDP + lc) = av;
      bf16x8 bv = *reinterpret_cast<const bf16x8*>(Bm + (size_t)(n0 + row) * K + k0 + lc);
      *reinterpret_cast<bf16x8*>(Bs + row * LDP + lc) = bv;
    }
    __syncthreads();
#pragma unroll
    for (int kb = 0; kb < 2; ++kb) {
      bf16x8 af[4], bf[4];
#pragma unroll
      for (int i = 0; i < 4; ++i)
        af[i] = *reinterpret_cast<const bf16x8*>(As + (wm + i * 16 + l16) * LDP + kb * 32 + quad * 8);
#pragma unroll
      for (int j = 0; j < 4; ++j)
        bf[j] = *reinterpret_cast<const bf16x8*>(Bs + (wn + j * 16 + l16) * LDP + kb * 32 + quad * 8);
#pragma unroll
      for (int i = 0; i < 4; ++i)
#pragma unroll
        for (int j = 0; j < 4; ++j)
          acc[i][j] = __builtin_amdgcn_mfma_f32_16x16x32_bf16(af[i], bf[j], acc[i][j], 0, 0, 0);
    }
  }

  // epilogue: C/D layout col = l16, row = quad*4 + r  [measured m89/m91]
#pragma unroll
  for (int i = 0; i < 4; ++i) {
    int mbase = m0 + wm + i * 16 + quad * 4;
#pragma unroll
    for (int j = 0; j < 4; ++j) {
      int f = n0 + wn + j * 16 + l16;
#pragma unroll
      for (int r = 0; r < 4; ++r) {
        float c = acc[i][j][r];
        int m = mbase + r;
        if (mode == 0) {
          int b = m >> 11, t = m & 2047;          // T = 2048
          int which = f / 768;
          int f2 = f - which * 768;
          int h = f2 >> 6, d = f2 & 63;
          int bh = b * 12 + h;
          unsigned short val = f2b(c);
          if (which == 0)      qb[((size_t)(bh * 2048 + t)) * 64 + d] = val;
          else if (which == 1) kb_[((size_t)(bh * 2048 + t)) * 64 + d] = val;
          else                 vt[((size_t)(bh * 64 + d)) * 2048 + t] = val;
        } else {
          outf[(size_t)m * N + f] = c;
        }
      }
    }
  }
}

// Flash-style causal attention.
// Qb,Kb: [BH=24][T=2048][D=64] bf16, Vt: [BH][D][T] bf16, Yb: [B,T,C] bf16 out.
// Block: 256 thr = 4 waves; 64 Q-rows per block (16 per wave); K-tiles of 64.
#define AT_LDP 88

__global__ __launch_bounds__(256)
void attn(const unsigned short* __restrict__ Qb,
          const unsigned short* __restrict__ Kb,
          const unsigned short* __restrict__ Vt,
          unsigned short* __restrict__ Yb) {
  __shared__ unsigned short Pl[4 * 16 * AT_LDP];
  const int T = 2048, D = 64;
  int tid = threadIdx.x;
  int wave = tid >> 6, lane = tid & 63;
  int quad = lane >> 4, l16 = lane & 15;
  int bh = blockIdx.y;
  int b = bh / 12, h = bh % 12;
  int q0 = blockIdx.x * 64;
  int qrow = q0 + wave * 16;  // wave's first Q row

  const unsigned short* Qp = Qb + (size_t)bh * T * D;
  const unsigned short* Kp = Kb + (size_t)bh * T * D;
  const unsigned short* Vp = Vt + (size_t)bh * D * T;
  unsigned short* Pw = Pl + wave * 16 * AT_LDP;

  // Q fragments (A-operand layout: m=l16, k=quad*8+j) straight from global
  bf16x8 aq0 = *reinterpret_cast<const bf16x8*>(Qp + (qrow + l16) * D + quad * 8);
  bf16x8 aq1 = *reinterpret_cast<const bf16x8*>(Qp + (qrow + l16) * D + 32 + quad * 8);

  f32x4 o[4] = {};
  float ms[4], ls[4];
#pragma unroll
  for (int r = 0; r < 4; ++r) { ms[r] = -1e30f; ls[r] = 0.f; }

  const float scale = 0.125f;  // 1/sqrt(64)

  for (int k0 = 0; k0 <= q0; k0 += 64) {
    // S = Q K^T  (16 q-rows x 64 keys per wave)
    f32x4 sacc[4] = {};
#pragma unroll
    for (int nt = 0; nt < 4; ++nt) {
      const unsigned short* kr = Kp + (k0 + nt * 16 + l16) * D + quad * 8;
      bf16x8 bk0 = *reinterpret_cast<const bf16x8*>(kr);
      bf16x8 bk1 = *reinterpret_cast<const bf16x8*>(kr + 32);
      sacc[nt] = __builtin_amdgcn_mfma_f32_16x16x32_bf16(aq0, bk0, sacc[nt], 0, 0, 0);
      sacc[nt] = __builtin_amdgcn_mfma_f32_16x16x32_bf16(aq1, bk1, sacc[nt], 0, 0, 0);
    }
    // scale + causal mask + row max
    float sv[4][4], rm[4];
#pragma unroll
    for (int r = 0; r < 4; ++r) rm[r] = -1e30f;
#pragma unroll
    for (int nt = 0; nt < 4; ++nt) {
      int col = k0 + nt * 16 + l16;
#pragma unroll
      for (int r = 0; r < 4; ++r) {
        int row = qrow + quad * 4 + r;
        float s = sacc[nt][r] * scale;
        s = (col <= row) ? s : -1e30f;
        sv[nt][r] = s;
        rm[r] = fmaxf(rm[r], s);
      }
    }
#pragma unroll
    for (int off = 1; off < 16; off <<= 1)
#pragma unroll
      for (int r = 0; r < 4; ++r)
        rm[r] = fmaxf(rm[r], __shfl_xor(rm[r], off, 16));
    // online softmax update
    float alpha[4], rs[4];
#pragma unroll
    for (int r = 0; r < 4; ++r) {
      float mnew = fmaxf(ms[r], rm[r]);
      alpha[r] = __expf(ms[r] - mnew);
      ms[r] = mnew;
      rs[r] = 0.f;
    }
#pragma unroll
    for (int nt = 0; nt < 4; ++nt)
#pragma unroll
      for (int r = 0; r < 4; ++r) {
        float p = __expf(sv[nt][r] - ms[r]);
        sv[nt][r] = p;
        rs[r] += p;
      }
#pragma unroll
    for (int off = 1; off < 16; off <<= 1)
#pragma unroll
      for (int r = 0; r < 4; ++r)
        rs[r] += __shfl_xor(rs[r], off, 16);
#pragma unroll
    for (int r = 0; r < 4; ++r) ls[r] = ls[r] * alpha[r] + rs[r];
#pragma unroll
    for (int dt = 0; dt < 4; ++dt)
#pragma unroll
      for (int r = 0; r < 4; ++r) o[dt][r] *= alpha[r];

    // P: C-layout -> LDS -> A-layout (verified m120 pattern)
    __syncthreads();
#pragma unroll
    for (int nt = 0; nt < 4; ++nt)
#pragma unroll
      for (int r = 0; r < 4; ++r)
        Pw[(quad * 4 + r) * AT_LDP + nt * 16 + l16] = f2b(sv[nt][r]);
    __syncthreads();

    // O += P V  (V^T frags contiguous from pre-transposed Vt)
#pragma unroll
    for (int kbb = 0; kbb < 2; ++kbb) {
      bf16x8 ap = *reinterpret_cast<const bf16x8*>(Pw + l16 * AT_LDP + kbb * 32 + quad * 8);
#pragma unroll
      for (int dt = 0; dt < 4; ++dt) {
        bf16x8 bv = *reinterpret_cast<const bf16x8*>(Vp + (size_t)(dt * 16 + l16) * T + k0 + kbb * 32 + quad * 8);
        o[dt] = __builtin_amdgcn_mfma_f32_16x16x32_bf16(ap, bv, o[dt], 0, 0, 0);
      }
    }
  }

  // epilogue: Yb[b, t, h*64+d] bf16
#pragma unroll
  for (int dt = 0; dt < 4; ++dt)
#pragma unroll
    for (int r = 0; r < 4; ++r) {
      int row = qrow + quad * 4 + r;
      float y = o[dt][r] / ls[r];
      Yb[((size_t)(b * T + row)) * 768 + h * 64 + dt * 16 + l16] = f2b(y);
    }
}

extern "C" void kernel_launch(void* const* d_in, const int* in_sizes, int n_in,
                              void* d_out, int out_size, void* d_ws, size_t ws_size,
                              hipStream_t stream) {
  const float* x  = (const float*)d_in[0];   // [2,2048,768]
  const float* Wa = (const float*)d_in[1];   // [2304,768]
  const float* Wp = (const float*)d_in[2];   // [768,768]
  float* out = (float*)d_out;                // [2,2048,768] fp32

  unsigned short* ws = (unsigned short*)d_ws;
  unsigned short* xb  = ws;                  // 4096*768
  unsigned short* Wab = xb  + 3145728;       // 2304*768
  unsigned short* Wpb = Wab + 1769472;       // 768*768
  unsigned short* Qb  = Wpb + 589824;        // 24*2048*64
  unsigned short* Kb  = Qb  + 3145728;
  unsigned short* Vt  = Kb  + 3145728;       // [24][64][2048]
  unsigned short* Yb  = Vt  + 3145728;       // 4096*768

  cvt4<<<3145728 / 4 / 256, 256, 0, stream>>>(x,  xb,  3145728 / 4);
  cvt4<<<1769472 / 4 / 256, 256, 0, stream>>>(Wa, Wab, 1769472 / 4);
  cvt4<<<589824  / 4 / 256, 256, 0, stream>>>(Wp, Wpb, 589824 / 4);

  // qkv = x @ W_attn^T, scattered to Qb/Kb/Vt
  gemm_nt<<<dim3(4096 / BM, 2304 / BN), 256, 0, stream>>>(
      xb, Wab, 4096, 2304, 768, 0, Qb, Kb, Vt, nullptr);

  attn<<<dim3(2048 / 64, 24), 256, 0, stream>>>(Qb, Kb, Vt, Yb);

  // y = y_att @ W_proj^T -> fp32 out
  gemm_nt<<<dim3(4096 / BM, 768 / BN), 256, 0, stream>>>(
      Yb, Wpb, 4096, 768, 768, 1, nullptr, nullptr, nullptr, out);
}

// Round 2
// 229.654 us; speedup vs baseline: 1.2959x; 1.2959x over previous
//
#include <hip/hip_runtime.h>

typedef __attribute__((ext_vector_type(8))) short bf16x8;
typedef __attribute__((ext_vector_type(4))) float f32x4;

// fp32 -> bf16 (round-to-nearest-even), finite inputs only
__device__ __forceinline__ unsigned short f2b(float f) {
  union { float f; unsigned u; } v; v.f = f;
  return (unsigned short)((v.u + 0x7FFFu + ((v.u >> 16) & 1u)) >> 16);
}

__global__ void cvt4(const float* __restrict__ in, unsigned short* __restrict__ out, int n4) {
  int i = blockIdx.x * 256 + threadIdx.x;
  if (i >= n4) return;
  float4 f = reinterpret_cast<const float4*>(in)[i];
  ushort4 o;
  o.x = f2b(f.x); o.y = f2b(f.y); o.z = f2b(f.z); o.w = f2b(f.w);
  reinterpret_cast<ushort4*>(out)[i] = o;
}

// C = A * B^T.  A: [M][K] bf16 row-major, Bm: [N][K] bf16 row-major.
// mode 0: qkv scatter epilogue -> Qb/Kb [B,H,T,D], Vt [B,H,D,T] (bf16)
// mode 1: fp32 row-major [M][N] to outf
#define BM 128
#define BN 128
#define BK 64
#define LDP 88  // padded LDS row pitch (elements): 176B = 16B-aligned, breaks bank conflicts

__global__ __launch_bounds__(256, 2)
void gemm_nt(const unsigned short* __restrict__ A,
             const unsigned short* __restrict__ Bm,
             int M, int N, int K, int mode,
             unsigned short* __restrict__ qb,
             unsigned short* __restrict__ kb_,
             unsigned short* __restrict__ vt,
             float* __restrict__ outf) {
  __shared__ unsigned short As[BM * LDP];
  __shared__ unsigned short Bs[BN * LDP];
  int tid = threadIdx.x;
  int wave = tid >> 6, lane = tid & 63;
  int quad = lane >> 4, l16 = lane & 15;
  int m0 = blockIdx.x * BM, n0 = blockIdx.y * BN;
  int wm = (wave & 1) * 64, wn = (wave >> 1) * 64;

  f32x4 acc[4][4] = {};

  int lr = tid >> 3;        // 0..31 (row within 32-row group)
  int lc = (tid & 7) * 8;   // 0,8,...,56 (k-offset)

  for (int k0 = 0; k0 < K; k0 += BK) {
    __syncthreads();
#pragma unroll
    for (int rr = 0; rr < 4; ++rr) {
      int row = lr + rr * 32;
      bf16x8 av = *reinterpret_cast<const bf16x8*>(A + (size_t)(m0 + row) * K + k0 + lc);
      *reinterpret_cast<bf16x8*>(As + row * LDP + lc) = av;
      bf16x8 bv = *reinterpret_cast<const bf16x8*>(Bm + (size_t)(n0 + row) * K + k0 + lc);
      *reinterpret_cast<bf16x8*>(Bs + row * LDP + lc) = bv;
    }
    __syncthreads();
#pragma unroll
    for (int kb = 0; kb < 2; ++kb) {
      bf16x8 af[4], bf[4];
#pragma unroll
      for (int i = 0; i < 4; ++i)
        af[i] = *reinterpret_cast<const bf16x8*>(As + (wm + i * 16 + l16) * LDP + kb * 32 + quad * 8);
#pragma unroll
      for (int j = 0; j < 4; ++j)
        bf[j] = *reinterpret_cast<const bf16x8*>(Bs + (wn + j * 16 + l16) * LDP + kb * 32 + quad * 8);
#pragma unroll
      for (int i = 0; i < 4; ++i)
#pragma unroll
        for (int j = 0; j < 4; ++j)
          acc[i][j] = __builtin_amdgcn_mfma_f32_16x16x32_bf16(af[i], bf[j], acc[i][j], 0, 0, 0);
    }
  }

  // epilogue: C/D layout col = l16, row = quad*4 + r  [measured m89/m91]
#pragma unroll
  for (int i = 0; i < 4; ++i) {
    int mbase = m0 + wm + i * 16 + quad * 4;
#pragma unroll
    for (int j = 0; j < 4; ++j) {
      int f = n0 + wn + j * 16 + l16;
#pragma unroll
      for (int r = 0; r < 4; ++r) {
        float c = acc[i][j][r];
        int m = mbase + r;
        if (mode == 0) {
          int b = m >> 11, t = m & 2047;          // T = 2048
          int which = f / 768;
          int f2 = f - which * 768;
          int h = f2 >> 6, d = f2 & 63;
          int bh = b * 12 + h;
          unsigned short val = f2b(c);
          if (which == 0)      qb[((size_t)(bh * 2048 + t)) * 64 + d] = val;
          else if (which == 1) kb_[((size_t)(bh * 2048 + t)) * 64 + d] = val;
          else                 vt[((size_t)(bh * 64 + d)) * 2048 + t] = val;
        } else {
          outf[(size_t)m * N + f] = c;
        }
      }
    }
  }
}

// Flash-style causal attention, one independent wave per block.
// Each wave: 32 Q-rows (2 A-frags), iterates 64-key tiles. No __syncthreads:
// the P transpose (C-layout -> A-layout) round-trips wave-private LDS with a
// wave-local lgkmcnt wait only.
// Qb,Kb: [BH=24][T=2048][D=64] bf16, Vt: [BH][D][T] bf16, Yb: [B,T,C] bf16.
#define AT_LDP 72  // 144 B pitch: 16B-aligned for ds_read_b128

__global__ __launch_bounds__(64)
void attn(const unsigned short* __restrict__ Qb,
          const unsigned short* __restrict__ Kb,
          const unsigned short* __restrict__ Vt,
          unsigned short* __restrict__ Yb) {
  __shared__ unsigned short P[32 * AT_LDP];
  const int T = 2048, D = 64;
  int lane = threadIdx.x;
  int quad = lane >> 4, l16 = lane & 15;
  int bh = blockIdx.y;
  int b = bh / 12, h = bh % 12;
  // reversed order: longest (highest q) blocks dispatch first
  int qc = (int)gridDim.x - 1 - (int)blockIdx.x;
  int qrow = qc * 32;

  const unsigned short* Qp = Qb + (size_t)bh * T * D;
  const unsigned short* Kp = Kb + (size_t)bh * T * D;
  const unsigned short* Vp = Vt + (size_t)bh * D * T;

  // Q fragments (A-layout: m=l16, k=quad*8+j), qi = which 16-row group
  bf16x8 aq[2][2];
#pragma unroll
  for (int qi = 0; qi < 2; ++qi)
#pragma unroll
    for (int c = 0; c < 2; ++c)
      aq[qi][c] = *reinterpret_cast<const bf16x8*>(
          Qp + (qrow + qi * 16 + l16) * D + c * 32 + quad * 8);

  f32x4 o[2][4] = {};
  float ms[2][4], ls[2][4];
#pragma unroll
  for (int qi = 0; qi < 2; ++qi)
#pragma unroll
    for (int r = 0; r < 4; ++r) { ms[qi][r] = -1e30f; ls[qi][r] = 0.f; }

  const float scale = 0.125f;  // 1/sqrt(64)
  int kmax = qrow + 31;

  for (int k0 = 0; k0 <= kmax; k0 += 64) {
    // ---- S = Q K^T : 2 qi x 4 nt accumulators (32 rows x 64 keys) ----
    bf16x8 kf[4][2];
#pragma unroll
    for (int nt = 0; nt < 4; ++nt) {
      const unsigned short* kr = Kp + (k0 + nt * 16 + l16) * D + quad * 8;
      kf[nt][0] = *reinterpret_cast<const bf16x8*>(kr);
      kf[nt][1] = *reinterpret_cast<const bf16x8*>(kr + 32);
    }
    f32x4 sacc[2][4] = {};
#pragma unroll
    for (int qi = 0; qi < 2; ++qi)
#pragma unroll
      for (int nt = 0; nt < 4; ++nt) {
        sacc[qi][nt] = __builtin_amdgcn_mfma_f32_16x16x32_bf16(aq[qi][0], kf[nt][0], sacc[qi][nt], 0, 0, 0);
        sacc[qi][nt] = __builtin_amdgcn_mfma_f32_16x16x32_bf16(aq[qi][1], kf[nt][1], sacc[qi][nt], 0, 0, 0);
      }

    // ---- scale + causal mask + online softmax (rows split across l16 via shfl) ----
    float sv[2][4][4], rm[2][4];
#pragma unroll
    for (int qi = 0; qi < 2; ++qi)
#pragma unroll
      for (int r = 0; r < 4; ++r) rm[qi][r] = -1e30f;
#pragma unroll
    for (int qi = 0; qi < 2; ++qi)
#pragma unroll
      for (int nt = 0; nt < 4; ++nt) {
        int col = k0 + nt * 16 + l16;
#pragma unroll
        for (int r = 0; r < 4; ++r) {
          int row = qrow + qi * 16 + quad * 4 + r;
          float s = sacc[qi][nt][r] * scale;
          s = (col <= row) ? s : -1e30f;
          sv[qi][nt][r] = s;
          rm[qi][r] = fmaxf(rm[qi][r], s);
        }
      }
#pragma unroll
    for (int off = 1; off < 16; off <<= 1)
#pragma unroll
      for (int qi = 0; qi < 2; ++qi)
#pragma unroll
        for (int r = 0; r < 4; ++r)
          rm[qi][r] = fmaxf(rm[qi][r], __shfl_xor(rm[qi][r], off, 16));

    float alpha[2][4], rs[2][4];
#pragma unroll
    for (int qi = 0; qi < 2; ++qi)
#pragma unroll
      for (int r = 0; r < 4; ++r) {
        float mnew = fmaxf(ms[qi][r], rm[qi][r]);
        alpha[qi][r] = __expf(ms[qi][r] - mnew);
        ms[qi][r] = mnew;
        rs[qi][r] = 0.f;
      }
#pragma unroll
    for (int qi = 0; qi < 2; ++qi)
#pragma unroll
      for (int nt = 0; nt < 4; ++nt)
#pragma unroll
        for (int r = 0; r < 4; ++r) {
          float p = __expf(sv[qi][nt][r] - ms[qi][r]);
          sv[qi][nt][r] = p;
          rs[qi][r] += p;
        }
#pragma unroll
    for (int off = 1; off < 16; off <<= 1)
#pragma unroll
      for (int qi = 0; qi < 2; ++qi)
#pragma unroll
        for (int r = 0; r < 4; ++r)
          rs[qi][r] += __shfl_xor(rs[qi][r], off, 16);
#pragma unroll
    for (int qi = 0; qi < 2; ++qi) {
#pragma unroll
      for (int r = 0; r < 4; ++r) ls[qi][r] = ls[qi][r] * alpha[qi][r] + rs[qi][r];
#pragma unroll
      for (int dt = 0; dt < 4; ++dt)
#pragma unroll
        for (int r = 0; r < 4; ++r) o[qi][dt][r] *= alpha[qi][r];
    }

    // ---- P: C-layout -> wave-private LDS -> A-layout (no block barrier) ----
#pragma unroll
    for (int qi = 0; qi < 2; ++qi)
#pragma unroll
      for (int nt = 0; nt < 4; ++nt)
#pragma unroll
        for (int r = 0; r < 4; ++r)
          P[(qi * 16 + quad * 4 + r) * AT_LDP + nt * 16 + l16] = f2b(sv[qi][nt][r]);
    __asm__ volatile("s_waitcnt lgkmcnt(0)" ::: "memory");

    // ---- O += P V (V frags contiguous from pre-transposed Vt) ----
    bf16x8 vf[4][2];
#pragma unroll
    for (int dt = 0; dt < 4; ++dt) {
      const unsigned short* vr = Vp + (size_t)(dt * 16 + l16) * T + k0 + quad * 8;
      vf[dt][0] = *reinterpret_cast<const bf16x8*>(vr);
      vf[dt][1] = *reinterpret_cast<const bf16x8*>(vr + 32);
    }
#pragma unroll
    for (int qi = 0; qi < 2; ++qi) {
      bf16x8 ap0 = *reinterpret_cast<const bf16x8*>(P + (qi * 16 + l16) * AT_LDP + quad * 8);
      bf16x8 ap1 = *reinterpret_cast<const bf16x8*>(P + (qi * 16 + l16) * AT_LDP + 32 + quad * 8);
#pragma unroll
      for (int dt = 0; dt < 4; ++dt) {
        o[qi][dt] = __builtin_amdgcn_mfma_f32_16x16x32_bf16(ap0, vf[dt][0], o[qi][dt], 0, 0, 0);
        o[qi][dt] = __builtin_amdgcn_mfma_f32_16x16x32_bf16(ap1, vf[dt][1], o[qi][dt], 0, 0, 0);
      }
    }
    __asm__ volatile("" ::: "memory");  // keep LDS reads of this iter before next iter's writes
  }

  // epilogue: Yb[b, t, h*64+d] bf16
#pragma unroll
  for (int qi = 0; qi < 2; ++qi)
#pragma unroll
    for (int dt = 0; dt < 4; ++dt)
#pragma unroll
      for (int r = 0; r < 4; ++r) {
        int row = qrow + qi * 16 + quad * 4 + r;
        float y = o[qi][dt][r] / ls[qi][r];
        Yb[((size_t)(b * T + row)) * 768 + h * 64 + dt * 16 + l16] = f2b(y);
      }
}

extern "C" void kernel_launch(void* const* d_in, const int* in_sizes, int n_in,
                              void* d_out, int out_size, void* d_ws, size_t ws_size,
                              hipStream_t stream) {
  const float* x  = (const float*)d_in[0];   // [2,2048,768]
  const float* Wa = (const float*)d_in[1];   // [2304,768]
  const float* Wp = (const float*)d_in[2];   // [768,768]
  float* out = (float*)d_out;                // [2,2048,768] fp32

  unsigned short* ws = (unsigned short*)d_ws;
  unsigned short* xb  = ws;                  // 4096*768
  unsigned short* Wab = xb  + 3145728;       // 2304*768
  unsigned short* Wpb = Wab + 1769472;       // 768*768
  unsigned short* Qb  = Wpb + 589824;        // 24*2048*64
  unsigned short* Kb  = Qb  + 3145728;
  unsigned short* Vt  = Kb  + 3145728;       // [24][64][2048]
  unsigned short* Yb  = Vt  + 3145728;       // 4096*768

  cvt4<<<3145728 / 4 / 256, 256, 0, stream>>>(x,  xb,  3145728 / 4);
  cvt4<<<1769472 / 4 / 256, 256, 0, stream>>>(Wa, Wab, 1769472 / 4);
  cvt4<<<589824  / 4 / 256, 256, 0, stream>>>(Wp, Wpb, 589824 / 4);

  // qkv = x @ W_attn^T, scattered to Qb/Kb/Vt
  gemm_nt<<<dim3(4096 / BM, 2304 / BN), 256, 0, stream>>>(
      xb, Wab, 4096, 2304, 768, 0, Qb, Kb, Vt, nullptr);

  attn<<<dim3(64, 24), 64, 0, stream>>>(Qb, Kb, Vt, Yb);

  // y = y_att @ W_proj^T -> fp32 out
  gemm_nt<<<dim3(4096 / BM, 768 / BN), 256, 0, stream>>>(
      Yb, Wpb, 4096, 768, 768, 1, nullptr, nullptr, nullptr, out);
}